// Round 9
// baseline (13163.210 us; speedup 1.0000x reference)
//
#include <hip/hip_runtime.h>

typedef float f4 __attribute__((ext_vector_type(4)));

#define EPSF 1e-5f
#define CIN   256
#define COUT  512
#define HIN   28
#define WIN_  28
#define HO    14
#define WO    14
#define HWO   196
#define NPIX  6272              // 32*14*14 (one app)
#define MROWS 31360             // 5 apps * NPIX
#define MTIL  245               // 31360/128 exact

#define BMr  128                // rows per block
#define BNc  64                 // oc per block (2 halves of 32)
#define BNh  32                 // oc per thread
#define BKC  32                 // k per step
#define LROW 132                // LDS row stride: 132%32=4 -> conflict-free writes

#define NS1  72                 // conv1: 9 taps * 8 chunks of 32
#define NS2  152                // conv2: 9*16 + ds: 8

// ---------------- prep kernels ----------------

__global__ __launch_bounds__(256)
void fold_bias_k(const float* __restrict__ g, const float* __restrict__ b,
                 const float* __restrict__ m, const float* __restrict__ v,
                 float* __restrict__ out)
{
  int oc = blockIdx.x * 256 + threadIdx.x;
  if (oc < COUT) {
    float s = g[oc] / sqrtf(v[oc] + EPSF);
    out[oc] = b[oc] - m[oc] * s;
  }
}

__global__ __launch_bounds__(256)
void fold_w_k(const float* __restrict__ w, const float* __restrict__ g,
              const float* __restrict__ v, float* __restrict__ out,
              int Ci, int taps)
{
  int idx = blockIdx.x * 256 + threadIdx.x;
  int total = taps * Ci * COUT;
  if (idx >= total) return;
  int oc  = idx % COUT;
  int c   = (idx / COUT) % Ci;
  int tap = idx / (COUT * Ci);
  float s = g[oc] / sqrtf(v[oc] + EPSF);
  out[idx] = w[((size_t)oc * Ci + c) * taps + tap] * s;
}

// ---------------- conv1 batched over 5 apps (3x3 s2 p1) ----------------
// blockIdx.x = oc-tile (8) -> XCD-pinned weights; blockIdx.y = M-tile (245).

__global__ __launch_bounds__(256)
void conv1b_k(const float* __restrict__ XS,   // inp_s (4,32,256,28,28)
              const float* __restrict__ XC,   // inp_c (32,256,28,28)
              const float* __restrict__ W1,   // [tap][c][oc]
              float* __restrict__ IO)         // [31360][512]
{
  __shared__ float lds[BKC * LROW];
  const int tid     = threadIdx.x;
  const int oc0     = blockIdx.x * BNc + (tid >> 7) * BNh;  // this thread's 32-oc slice
  const int tl      = tid & 127;                            // this thread's row
  const int rowBase = blockIdx.y * BMr;

  float acc[BNh];
  #pragma unroll
  for (int j = 0; j < BNh; j++) acc[j] = 0.f;

  // staging map: srow = tid>>2 (0..63), slot = tid&3; rows srow+64p, k = q*16+slot*4+j
  const int srow = tid >> 2;
  const int slot = tid & 3;

  const float* gbase[2]; int gho[2], gwo[2];
  #pragma unroll
  for (int p = 0; p < 2; p++) {
    int r = rowBase + srow + 64 * p;
    int app = r / NPIX; int pp = r - app * NPIX;
    int b = pp / HWO; int hw = pp - b * HWO;
    gho[p] = hw / WO; gwo[p] = hw - gho[p] * WO;
    gbase[p] = (app < 4) ? (XS + (size_t)(app * 32 + b) * (CIN * 784))
                         : (XC + (size_t)b * (CIN * 784));
  }

  f4 vreg[4];                    // [p][q]

  auto issue = [&](int s) {
    int tap = s >> 3, c0 = (s & 7) << 5;
    int kh = tap / 3, kw = tap - (tap / 3) * 3;
    #pragma unroll
    for (int p = 0; p < 2; p++) {
      int hi = 2 * gho[p] + kh - 1, wi = 2 * gwo[p] + kw - 1;
      bool v = ((unsigned)hi < (unsigned)HIN) && ((unsigned)wi < (unsigned)WIN_);
      #pragma unroll
      for (int q = 0; q < 2; q++) {
        const float* sp_ = gbase[p] + (size_t)(c0 + q * 16 + slot * 4) * 784 + hi * WIN_ + wi;
        f4 val;
        #pragma unroll
        for (int j = 0; j < 4; j++) val[j] = v ? sp_[(size_t)j * 784] : 0.f;
        vreg[p * 2 + q] = val;
      }
    }
  };

  auto write_lds = [&]() {
    #pragma unroll
    for (int p = 0; p < 2; p++)
      #pragma unroll
      for (int q = 0; q < 2; q++)
        #pragma unroll
        for (int j = 0; j < 4; j++)
          lds[(q * 16 + slot * 4 + j) * LROW + srow + 64 * p] = vreg[p * 2 + q][j];
  };

  auto gemm_step = [&](const float* __restrict__ wb) {
    #pragma unroll 2
    for (int k = 0; k < BKC; k++) {
      float a = lds[k * LROW + tl];
      const float* __restrict__ wr = wb + (size_t)k * COUT;   // lane-uniform -> s_load
      #pragma unroll
      for (int j = 0; j < BNh; j++) acc[j] = fmaf(a, wr[j], acc[j]);
    }
  };

  issue(0);
  for (int s = 0; s < NS1; ++s) {
    __syncthreads();
    write_lds();
    __syncthreads();
    if (s < NS1 - 1) issue(s + 1);
    int tap = s >> 3, c0 = (s & 7) << 5;
    gemm_step(W1 + ((size_t)tap * CIN + c0) * COUT + oc0);
  }

  const int r = rowBase + tl;
  #pragma unroll
  for (int j = 0; j < BNh; j += 4) {
    f4 v = {acc[j], acc[j + 1], acc[j + 2], acc[j + 3]};
    *(f4*)&IO[(size_t)r * COUT + oc0 + j] = v;
  }
}

// ---------------- layer-1 scan ----------------

__global__ __launch_bounds__(256)
void scan1_k(const float* __restrict__ IO, const float* __restrict__ b1v,
             const float* __restrict__ vth1,
             unsigned char* __restrict__ SP,   // [4][NPIX][512] u8
             float* __restrict__ ACT)          // [NPIX][512]
{
  int idx = blockIdx.x * 256 + threadIdx.x;
  int oc = idx & 511, pix = idx >> 9;
  int hw = pix % HWO;
  float b1 = b1v[oc], vt = vth1[oc * HWO + hw];
  float mem = 0.f; int m1 = 0;
  #pragma unroll
  for (int t = 0; t < 4; ++t) {
    float cur = IO[((size_t)t * NPIX + pix) * 512 + oc] + b1;
    mem += cur;
    float sp = (mem >= vt) ? 1.f : 0.f;
    mem -= sp * vt;
    m1 += (sp > 0.f) ? 1 : 0;
    SP[((size_t)t * NPIX + pix) * 512 + oc] = (unsigned char)sp;
  }
  float a = IO[((size_t)4 * NPIX + pix) * 512 + oc] + b1;
  a = a > 0.f ? a : 0.f;
  ACT[(size_t)pix * 512 + oc] = (m1 > 0) ? a : 0.f;
}

// ---------------- conv2 batched + ds fused along K ----------------

__global__ __launch_bounds__(256)
void conv2b_k(const unsigned char* __restrict__ SP,
              const float* __restrict__ ACT,
              const float* __restrict__ XS,
              const float* __restrict__ XC,
              const float* __restrict__ W2,
              const float* __restrict__ WD,
              float* __restrict__ IO)
{
  __shared__ float lds[BKC * LROW];
  const int tid     = threadIdx.x;
  const int oc0     = blockIdx.x * BNc + (tid >> 7) * BNh;
  const int tl      = tid & 127;
  const int rowBase = blockIdx.y * BMr;

  float acc[BNh];
  #pragma unroll
  for (int j = 0; j < BNh; j++) acc[j] = 0.f;

  const int srow = tid >> 2;
  const int slot = tid & 3;

  const float* gxbase[2]; int gapp[2], gb[2], gho[2], gwo[2];
  #pragma unroll
  for (int p = 0; p < 2; p++) {
    int r = rowBase + srow + 64 * p;
    int app = r / NPIX; int pp = r - app * NPIX;
    int b = pp / HWO; int hw = pp - b * HWO;
    gapp[p] = app; gb[p] = b;
    gho[p] = hw / WO; gwo[p] = hw - gho[p] * WO;
    gxbase[p] = (app < 4) ? (XS + (size_t)(app * 32 + b) * (CIN * 784))
                          : (XC + (size_t)b * (CIN * 784));
  }

  f4 vreg[4];

  auto issue = [&](int s) {
    if (s < 144) {
      int tap = s >> 4, c0 = (s & 15) << 5;
      int kh = tap / 3, kw = tap - (tap / 3) * 3;
      #pragma unroll
      for (int p = 0; p < 2; p++) {
        int hi = gho[p] + kh - 1, wi = gwo[p] + kw - 1;
        bool v = ((unsigned)hi < (unsigned)HO) && ((unsigned)wi < (unsigned)WO);
        int pix2 = gb[p] * HWO + hi * WO + wi;
        #pragma unroll
        for (int q = 0; q < 2; q++) {
          f4 val = {0.f, 0.f, 0.f, 0.f};
          int c = c0 + q * 16 + slot * 4;
          if (v) {
            if (gapp[p] < 4) {
              unsigned u = *(const unsigned*)(SP + ((size_t)gapp[p] * NPIX + pix2) * 512 + c);
              #pragma unroll
              for (int j = 0; j < 4; j++) val[j] = (float)((u >> (8 * j)) & 255u);
            } else {
              val = *(const f4*)(ACT + (size_t)pix2 * 512 + c);
            }
          }
          vreg[p * 2 + q] = val;
        }
      }
    } else {
      int c0 = (s - 144) << 5;
      #pragma unroll
      for (int p = 0; p < 2; p++) {
        int hi = 2 * gho[p], wi = 2 * gwo[p];
        #pragma unroll
        for (int q = 0; q < 2; q++) {
          const float* sp_ = gxbase[p] + (size_t)(c0 + q * 16 + slot * 4) * 784 + hi * WIN_ + wi;
          f4 val;
          #pragma unroll
          for (int j = 0; j < 4; j++) val[j] = sp_[(size_t)j * 784];
          vreg[p * 2 + q] = val;
        }
      }
    }
  };

  auto write_lds = [&]() {
    #pragma unroll
    for (int p = 0; p < 2; p++)
      #pragma unroll
      for (int q = 0; q < 2; q++)
        #pragma unroll
        for (int j = 0; j < 4; j++)
          lds[(q * 16 + slot * 4 + j) * LROW + srow + 64 * p] = vreg[p * 2 + q][j];
  };

  auto gemm_step = [&](const float* __restrict__ wb) {
    #pragma unroll 2
    for (int k = 0; k < BKC; k++) {
      float a = lds[k * LROW + tl];
      const float* __restrict__ wr = wb + (size_t)k * COUT;
      #pragma unroll
      for (int j = 0; j < BNh; j++) acc[j] = fmaf(a, wr[j], acc[j]);
    }
  };

  issue(0);
  for (int s = 0; s < NS2; ++s) {
    __syncthreads();
    write_lds();
    __syncthreads();
    if (s < NS2 - 1) issue(s + 1);
    const float* wb;
    if (s < 144) {
      int tap = s >> 4, c0 = (s & 15) << 5;
      wb = W2 + ((size_t)tap * COUT + c0) * COUT + oc0;
    } else {
      int c0 = (s - 144) << 5;
      wb = WD + (size_t)c0 * COUT + oc0;
    }
    gemm_step(wb);
  }

  const int r = rowBase + tl;
  #pragma unroll
  for (int j = 0; j < BNh; j += 4) {
    f4 v = {acc[j], acc[j + 1], acc[j + 2], acc[j + 3]};
    *(f4*)&IO[(size_t)r * COUT + oc0 + j] = v;
  }
}

// ---------------- final scan + outputs (NCHW) ----------------

__global__ __launch_bounds__(256)
void final_k(const float* __restrict__ IO, const float* __restrict__ b2v,
             const float* __restrict__ bdv, const float* __restrict__ vthif,
             float* __restrict__ out0, float* __restrict__ out1,
             float* __restrict__ out2)
{
  int idx = blockIdx.x * 256 + threadIdx.x;
  int oc = idx & 511, pix = idx >> 9;
  int hw = pix % HWO, b = pix / HWO;
  float bias = b2v[oc] + bdv[oc];
  float vt = vthif[oc * HWO + hw];
  float memf = 0.f; int m3 = 0; float o3 = 0.f, os3 = 0.f;
  #pragma unroll
  for (int t = 0; t < 4; ++t) {
    float os = IO[((size_t)t * NPIX + pix) * 512 + oc] + bias;
    memf += os;
    float sp = (memf >= vt) ? 1.f : 0.f;
    memf -= sp * vt;
    m3 += (sp > 0.f) ? 1 : 0;
    if (t == 3) { o3 = sp; os3 = os; }
  }
  size_t oidx = ((size_t)b * COUT + oc) * HWO + hw;
  out0[oidx] = o3;
  out1[oidx] = os3;
  float av = IO[((size_t)4 * NPIX + pix) * 512 + oc] + bias;
  av = av > 0.f ? av : 0.f;
  out2[oidx] = (m3 > 0) ? av : 0.f;
}

// ---------------- launcher ----------------

extern "C" void kernel_launch(void* const* d_in, const int* in_sizes, int n_in,
                              void* d_out, int out_size, void* d_ws, size_t ws_size,
                              hipStream_t stream)
{
  const float* inp_s = (const float*)d_in[0];
  const float* inp_c = (const float*)d_in[2];
  const float* w1    = (const float*)d_in[3];
  const float* w2    = (const float*)d_in[4];
  const float* wd    = (const float*)d_in[5];
  const float* bn1g = (const float*)d_in[6],  *bn1b = (const float*)d_in[7];
  const float* bn1m = (const float*)d_in[8],  *bn1v = (const float*)d_in[9];
  const float* bn2g = (const float*)d_in[10], *bn2b = (const float*)d_in[11];
  const float* bn2m = (const float*)d_in[12], *bn2v = (const float*)d_in[13];
  const float* dsg  = (const float*)d_in[14], *dsb  = (const float*)d_in[15];
  const float* dsm  = (const float*)d_in[16], *dsv  = (const float*)d_in[17];
  const float* vth1  = (const float*)d_in[18];
  const float* vthif = (const float*)d_in[21];

  float* ws = (float*)d_ws;
  size_t off = 0;
  float* W1T = ws + off; off += (size_t)9 * CIN * COUT;
  float* W2T = ws + off; off += (size_t)9 * COUT * COUT;
  float* WDT = ws + off; off += (size_t)CIN * COUT;
  float* B1V = ws + off; off += COUT;
  float* B2V = ws + off; off += COUT;
  float* BDV = ws + off; off += COUT;
  float* IO  = ws + off; off += (size_t)MROWS * COUT;
  float* ACT = ws + off; off += (size_t)NPIX * COUT;
  unsigned char* SP = (unsigned char*)(ws + off);
  // total ~104.6 MB, under the R1-proven 117.4 MB bound

  float* out0 = (float*)d_out;
  float* out1 = out0 + (size_t)NPIX * COUT;
  float* out2 = out1 + (size_t)NPIX * COUT;

  fold_bias_k<<<2, 256, 0, stream>>>(bn1g, bn1b, bn1m, bn1v, B1V);
  fold_bias_k<<<2, 256, 0, stream>>>(bn2g, bn2b, bn2m, bn2v, B2V);
  fold_bias_k<<<2, 256, 0, stream>>>(dsg,  dsb,  dsm,  dsv,  BDV);
  fold_w_k<<<(9 * CIN * COUT + 255) / 256, 256, 0, stream>>>(w1, bn1g, bn1v, W1T, CIN, 9);
  fold_w_k<<<(9 * COUT * COUT + 255) / 256, 256, 0, stream>>>(w2, bn2g, bn2v, W2T, COUT, 9);
  fold_w_k<<<(CIN * COUT + 255) / 256, 256, 0, stream>>>(wd, dsg, dsv, WDT, CIN, 1);

  dim3 cgrid(COUT / BNc, MTIL);                 // 8 x 245 : x = oc-slice -> XCD-pinned
  const int scanGrid = (NPIX * COUT) / 256;

  conv1b_k<<<cgrid, 256, 0, stream>>>(inp_s, inp_c, W1T, IO);
  scan1_k<<<scanGrid, 256, 0, stream>>>(IO, B1V, vth1, SP, ACT);
  conv2b_k<<<cgrid, 256, 0, stream>>>(SP, ACT, inp_s, inp_c, W2T, WDT, IO);
  final_k<<<scanGrid, 256, 0, stream>>>(IO, B2V, BDV, vthif, out0, out1, out2);
}

// Round 10
// 3591.019 us; speedup vs baseline: 3.6656x; 3.6656x over previous
//
#include <hip/hip_runtime.h>

typedef float f4 __attribute__((ext_vector_type(4)));

#define EPSF 1e-5f
#define CIN   256
#define COUT  512
#define HIN   28
#define WIN_  28
#define HO    14
#define WO    14
#define HWO   196
#define NPIX  6272              // 32*14*14 (one app)
#define MROWS 31360             // 5 apps * NPIX
#define MTIL  245               // 31360/128 exact

#define BMr  128                // rows per block
#define BNc  64                 // oc per block (2 wave-halves of 32)
#define BNh  32                 // oc per thread
#define BKC  32                 // k per step
#define LROW 132                // LDS row stride

#define NS1  72                 // conv1: 9 taps * 8 chunks of 32
#define NS2  152                // conv2: 9*16 + ds: 8

// ---------------- prep kernels ----------------

__global__ __launch_bounds__(256)
void fold_bias_k(const float* __restrict__ g, const float* __restrict__ b,
                 const float* __restrict__ m, const float* __restrict__ v,
                 float* __restrict__ out)
{
  int oc = blockIdx.x * 256 + threadIdx.x;
  if (oc < COUT) {
    float s = g[oc] / sqrtf(v[oc] + EPSF);
    out[oc] = b[oc] - m[oc] * s;
  }
}

__global__ __launch_bounds__(256)
void fold_w_k(const float* __restrict__ w, const float* __restrict__ g,
              const float* __restrict__ v, float* __restrict__ out,
              int Ci, int taps)
{
  int idx = blockIdx.x * 256 + threadIdx.x;
  int total = taps * Ci * COUT;
  if (idx >= total) return;
  int oc  = idx % COUT;
  int c   = (idx / COUT) % Ci;
  int tap = idx / (COUT * Ci);
  float s = g[oc] / sqrtf(v[oc] + EPSF);
  out[idx] = w[((size_t)oc * Ci + c) * taps + tap] * s;
}

// ---------------- conv1 batched over 5 apps (3x3 s2 p1) ----------------
// blockIdx.x = oc-tile (8) -> XCD-pinned weights; blockIdx.y = M-tile (245).
// oc half index forced into SGPR via readfirstlane -> weight loads stay s_load.

__global__ __launch_bounds__(256)
void conv1b_k(const float* __restrict__ XS,   // inp_s (4,32,256,28,28)
              const float* __restrict__ XC,   // inp_c (32,256,28,28)
              const float* __restrict__ W1,   // [tap][c][oc]
              float* __restrict__ IO)         // [31360][512]
{
  __shared__ float lds[BKC * LROW];
  const int tid  = threadIdx.x;
  const int half = __builtin_amdgcn_readfirstlane(tid >> 7);  // wave-uniform -> SGPR
  const int oc0  = blockIdx.x * BNc + half * BNh;
  const int tl   = tid & 127;
  const int rowBase = blockIdx.y * BMr;

  float acc[BNh];
  #pragma unroll
  for (int j = 0; j < BNh; j++) acc[j] = 0.f;

  const int srow = tid >> 2;
  const int slot = tid & 3;

  const float* gbase[2]; int gho[2], gwo[2];
  #pragma unroll
  for (int p = 0; p < 2; p++) {
    int r = rowBase + srow + 64 * p;
    int app = r / NPIX; int pp = r - app * NPIX;
    int b = pp / HWO; int hw = pp - b * HWO;
    gho[p] = hw / WO; gwo[p] = hw - gho[p] * WO;
    gbase[p] = (app < 4) ? (XS + (size_t)(app * 32 + b) * (CIN * 784))
                         : (XC + (size_t)b * (CIN * 784));
  }

  f4 vreg[4];                    // [p][q]

  auto issue = [&](int s) {
    int tap = s >> 3, c0 = (s & 7) << 5;
    int kh = tap / 3, kw = tap - (tap / 3) * 3;
    #pragma unroll
    for (int p = 0; p < 2; p++) {
      int hi = 2 * gho[p] + kh - 1, wi = 2 * gwo[p] + kw - 1;
      bool v = ((unsigned)hi < (unsigned)HIN) && ((unsigned)wi < (unsigned)WIN_);
      #pragma unroll
      for (int q = 0; q < 2; q++) {
        const float* sp_ = gbase[p] + (size_t)(c0 + q * 16 + slot * 4) * 784 + hi * WIN_ + wi;
        f4 val;
        #pragma unroll
        for (int j = 0; j < 4; j++) val[j] = v ? sp_[(size_t)j * 784] : 0.f;
        vreg[p * 2 + q] = val;
      }
    }
  };

  auto write_lds = [&]() {
    #pragma unroll
    for (int p = 0; p < 2; p++)
      #pragma unroll
      for (int q = 0; q < 2; q++)
        #pragma unroll
        for (int j = 0; j < 4; j++)
          lds[(q * 16 + slot * 4 + j) * LROW + srow + 64 * p] = vreg[p * 2 + q][j];
  };

  auto gemm_step = [&](const float* __restrict__ wb) {
    #pragma unroll 2
    for (int k = 0; k < BKC; k++) {
      float a = lds[k * LROW + tl];
      const float* __restrict__ wr = wb + (size_t)k * COUT;   // SGPR-uniform -> s_load
      #pragma unroll
      for (int j = 0; j < BNh; j++) acc[j] = fmaf(a, wr[j], acc[j]);
    }
  };

  issue(0);
  for (int s = 0; s < NS1; ++s) {
    __syncthreads();
    write_lds();
    __syncthreads();
    if (s < NS1 - 1) issue(s + 1);
    int tap = s >> 3, c0 = (s & 7) << 5;
    gemm_step(W1 + ((size_t)tap * CIN + c0) * COUT + oc0);
  }

  const int r = rowBase + tl;
  #pragma unroll
  for (int j = 0; j < BNh; j += 4) {
    f4 v = {acc[j], acc[j + 1], acc[j + 2], acc[j + 3]};
    *(f4*)&IO[(size_t)r * COUT + oc0 + j] = v;
  }
}

// ---------------- layer-1 scan ----------------

__global__ __launch_bounds__(256)
void scan1_k(const float* __restrict__ IO, const float* __restrict__ b1v,
             const float* __restrict__ vth1,
             unsigned char* __restrict__ SP,   // [4][NPIX][512] u8
             float* __restrict__ ACT)          // [NPIX][512]
{
  int idx = blockIdx.x * 256 + threadIdx.x;
  int oc = idx & 511, pix = idx >> 9;
  int hw = pix % HWO;
  float b1 = b1v[oc], vt = vth1[oc * HWO + hw];
  float mem = 0.f; int m1 = 0;
  #pragma unroll
  for (int t = 0; t < 4; ++t) {
    float cur = IO[((size_t)t * NPIX + pix) * 512 + oc] + b1;
    mem += cur;
    float sp = (mem >= vt) ? 1.f : 0.f;
    mem -= sp * vt;
    m1 += (sp > 0.f) ? 1 : 0;
    SP[((size_t)t * NPIX + pix) * 512 + oc] = (unsigned char)sp;
  }
  float a = IO[((size_t)4 * NPIX + pix) * 512 + oc] + b1;
  a = a > 0.f ? a : 0.f;
  ACT[(size_t)pix * 512 + oc] = (m1 > 0) ? a : 0.f;
}

// ---------------- conv2 batched + ds fused along K ----------------

__global__ __launch_bounds__(256)
void conv2b_k(const unsigned char* __restrict__ SP,
              const float* __restrict__ ACT,
              const float* __restrict__ XS,
              const float* __restrict__ XC,
              const float* __restrict__ W2,
              const float* __restrict__ WD,
              float* __restrict__ IO)
{
  __shared__ float lds[BKC * LROW];
  const int tid  = threadIdx.x;
  const int half = __builtin_amdgcn_readfirstlane(tid >> 7);  // wave-uniform -> SGPR
  const int oc0  = blockIdx.x * BNc + half * BNh;
  const int tl   = tid & 127;
  const int rowBase = blockIdx.y * BMr;

  float acc[BNh];
  #pragma unroll
  for (int j = 0; j < BNh; j++) acc[j] = 0.f;

  const int srow = tid >> 2;
  const int slot = tid & 3;

  const float* gxbase[2]; int gapp[2], gb[2], gho[2], gwo[2];
  #pragma unroll
  for (int p = 0; p < 2; p++) {
    int r = rowBase + srow + 64 * p;
    int app = r / NPIX; int pp = r - app * NPIX;
    int b = pp / HWO; int hw = pp - b * HWO;
    gapp[p] = app; gb[p] = b;
    gho[p] = hw / WO; gwo[p] = hw - gho[p] * WO;
    gxbase[p] = (app < 4) ? (XS + (size_t)(app * 32 + b) * (CIN * 784))
                          : (XC + (size_t)b * (CIN * 784));
  }

  f4 vreg[4];

  auto issue = [&](int s) {
    if (s < 144) {
      int tap = s >> 4, c0 = (s & 15) << 5;
      int kh = tap / 3, kw = tap - (tap / 3) * 3;
      #pragma unroll
      for (int p = 0; p < 2; p++) {
        int hi = gho[p] + kh - 1, wi = gwo[p] + kw - 1;
        bool v = ((unsigned)hi < (unsigned)HO) && ((unsigned)wi < (unsigned)WO);
        int pix2 = gb[p] * HWO + hi * WO + wi;
        #pragma unroll
        for (int q = 0; q < 2; q++) {
          f4 val = {0.f, 0.f, 0.f, 0.f};
          int c = c0 + q * 16 + slot * 4;
          if (v) {
            if (gapp[p] < 4) {
              unsigned u = *(const unsigned*)(SP + ((size_t)gapp[p] * NPIX + pix2) * 512 + c);
              #pragma unroll
              for (int j = 0; j < 4; j++) val[j] = (float)((u >> (8 * j)) & 255u);
            } else {
              val = *(const f4*)(ACT + (size_t)pix2 * 512 + c);
            }
          }
          vreg[p * 2 + q] = val;
        }
      }
    } else {
      int c0 = (s - 144) << 5;
      #pragma unroll
      for (int p = 0; p < 2; p++) {
        int hi = 2 * gho[p], wi = 2 * gwo[p];
        #pragma unroll
        for (int q = 0; q < 2; q++) {
          const float* sp_ = gxbase[p] + (size_t)(c0 + q * 16 + slot * 4) * 784 + hi * WIN_ + wi;
          f4 val;
          #pragma unroll
          for (int j = 0; j < 4; j++) val[j] = sp_[(size_t)j * 784];
          vreg[p * 2 + q] = val;
        }
      }
    }
  };

  auto write_lds = [&]() {
    #pragma unroll
    for (int p = 0; p < 2; p++)
      #pragma unroll
      for (int q = 0; q < 2; q++)
        #pragma unroll
        for (int j = 0; j < 4; j++)
          lds[(q * 16 + slot * 4 + j) * LROW + srow + 64 * p] = vreg[p * 2 + q][j];
  };

  auto gemm_step = [&](const float* __restrict__ wb) {
    #pragma unroll 2
    for (int k = 0; k < BKC; k++) {
      float a = lds[k * LROW + tl];
      const float* __restrict__ wr = wb + (size_t)k * COUT;   // SGPR-uniform -> s_load
      #pragma unroll
      for (int j = 0; j < BNh; j++) acc[j] = fmaf(a, wr[j], acc[j]);
    }
  };

  issue(0);
  for (int s = 0; s < NS2; ++s) {
    __syncthreads();
    write_lds();
    __syncthreads();
    if (s < NS2 - 1) issue(s + 1);
    const float* wb;
    if (s < 144) {
      int tap = s >> 4, c0 = (s & 15) << 5;
      wb = W2 + ((size_t)tap * COUT + c0) * COUT + oc0;
    } else {
      int c0 = (s - 144) << 5;
      wb = WD + (size_t)c0 * COUT + oc0;
    }
    gemm_step(wb);
  }

  const int r = rowBase + tl;
  #pragma unroll
  for (int j = 0; j < BNh; j += 4) {
    f4 v = {acc[j], acc[j + 1], acc[j + 2], acc[j + 3]};
    *(f4*)&IO[(size_t)r * COUT + oc0 + j] = v;
  }
}

// ---------------- final scan + outputs (NCHW) ----------------

__global__ __launch_bounds__(256)
void final_k(const float* __restrict__ IO, const float* __restrict__ b2v,
             const float* __restrict__ bdv, const float* __restrict__ vthif,
             float* __restrict__ out0, float* __restrict__ out1,
             float* __restrict__ out2)
{
  int idx = blockIdx.x * 256 + threadIdx.x;
  int oc = idx & 511, pix = idx >> 9;
  int hw = pix % HWO, b = pix / HWO;
  float bias = b2v[oc] + bdv[oc];
  float vt = vthif[oc * HWO + hw];
  float memf = 0.f; int m3 = 0; float o3 = 0.f, os3 = 0.f;
  #pragma unroll
  for (int t = 0; t < 4; ++t) {
    float os = IO[((size_t)t * NPIX + pix) * 512 + oc] + bias;
    memf += os;
    float sp = (memf >= vt) ? 1.f : 0.f;
    memf -= sp * vt;
    m3 += (sp > 0.f) ? 1 : 0;
    if (t == 3) { o3 = sp; os3 = os; }
  }
  size_t oidx = ((size_t)b * COUT + oc) * HWO + hw;
  out0[oidx] = o3;
  out1[oidx] = os3;
  float av = IO[((size_t)4 * NPIX + pix) * 512 + oc] + bias;
  av = av > 0.f ? av : 0.f;
  out2[oidx] = (m3 > 0) ? av : 0.f;
}

// ---------------- launcher ----------------

extern "C" void kernel_launch(void* const* d_in, const int* in_sizes, int n_in,
                              void* d_out, int out_size, void* d_ws, size_t ws_size,
                              hipStream_t stream)
{
  const float* inp_s = (const float*)d_in[0];
  const float* inp_c = (const float*)d_in[2];
  const float* w1    = (const float*)d_in[3];
  const float* w2    = (const float*)d_in[4];
  const float* wd    = (const float*)d_in[5];
  const float* bn1g = (const float*)d_in[6],  *bn1b = (const float*)d_in[7];
  const float* bn1m = (const float*)d_in[8],  *bn1v = (const float*)d_in[9];
  const float* bn2g = (const float*)d_in[10], *bn2b = (const float*)d_in[11];
  const float* bn2m = (const float*)d_in[12], *bn2v = (const float*)d_in[13];
  const float* dsg  = (const float*)d_in[14], *dsb  = (const float*)d_in[15];
  const float* dsm  = (const float*)d_in[16], *dsv  = (const float*)d_in[17];
  const float* vth1  = (const float*)d_in[18];
  const float* vthif = (const float*)d_in[21];

  float* ws = (float*)d_ws;
  size_t off = 0;
  float* W1T = ws + off; off += (size_t)9 * CIN * COUT;
  float* W2T = ws + off; off += (size_t)9 * COUT * COUT;
  float* WDT = ws + off; off += (size_t)CIN * COUT;
  float* B1V = ws + off; off += COUT;
  float* B2V = ws + off; off += COUT;
  float* BDV = ws + off; off += COUT;
  float* IO  = ws + off; off += (size_t)MROWS * COUT;
  float* ACT = ws + off; off += (size_t)NPIX * COUT;
  unsigned char* SP = (unsigned char*)(ws + off);
  // total ~104.6 MB, under the R1-proven 117.4 MB bound

  float* out0 = (float*)d_out;
  float* out1 = out0 + (size_t)NPIX * COUT;
  float* out2 = out1 + (size_t)NPIX * COUT;

  fold_bias_k<<<2, 256, 0, stream>>>(bn1g, bn1b, bn1m, bn1v, B1V);
  fold_bias_k<<<2, 256, 0, stream>>>(bn2g, bn2b, bn2m, bn2v, B2V);
  fold_bias_k<<<2, 256, 0, stream>>>(dsg,  dsb,  dsm,  dsv,  BDV);
  fold_w_k<<<(9 * CIN * COUT + 255) / 256, 256, 0, stream>>>(w1, bn1g, bn1v, W1T, CIN, 9);
  fold_w_k<<<(9 * COUT * COUT + 255) / 256, 256, 0, stream>>>(w2, bn2g, bn2v, W2T, COUT, 9);
  fold_w_k<<<(CIN * COUT + 255) / 256, 256, 0, stream>>>(wd, dsg, dsv, WDT, CIN, 1);

  dim3 cgrid(COUT / BNc, MTIL);                 // 8 x 245 : x = oc-slice -> XCD-pinned
  const int scanGrid = (NPIX * COUT) / 256;

  conv1b_k<<<cgrid, 256, 0, stream>>>(inp_s, inp_c, W1T, IO);
  scan1_k<<<scanGrid, 256, 0, stream>>>(IO, B1V, vth1, SP, ACT);
  conv2b_k<<<cgrid, 256, 0, stream>>>(SP, ACT, inp_s, inp_c, W2T, WDT, IO);
  final_k<<<scanGrid, 256, 0, stream>>>(IO, B2V, BDV, vthif, out0, out1, out2);
}